// Round 2
// baseline (875.001 us; speedup 1.0000x reference)
//
#include <hip/hip_runtime.h>
#include <math.h>

#define DIN 128
#define DOUT 64
#define WROW 132            // padded LDS row stride (floats) for 64x128 tiles
#define GROW 65             // padded LDS row stride for 64x64 G

__device__ __forceinline__ float safe_pow(float d, float e) {
    float p = powf(d, e);
    return isinf(p) ? 0.0f : p;
}

// ---------------------------------------------------------------------------
// Kernel 1: Bjorck orthogonalization of W (DOUT x DIN), single workgroup.
//   w = W / (1.1 * sigma_max(W)); 5x: w = 1.5 w - 0.5 (w w^T) w
// ---------------------------------------------------------------------------
__device__ void compute_G(const float* w_s, float* g_s, int t) {
    for (int idx = t; idx < DOUT * DOUT; idx += 256) {
        int i = idx >> 6, j = idx & 63;
        const float4* a4 = (const float4*)&w_s[i * WROW];
        const float4* b4 = (const float4*)&w_s[j * WROW];
        float s = 0.f;
#pragma unroll
        for (int k = 0; k < DIN / 4; ++k) {
            float4 a = a4[k], b = b4[k];
            s += a.x * b.x + a.y * b.y + a.z * b.z + a.w * b.w;
        }
        g_s[i * GROW + j] = s;
    }
}

__global__ __launch_bounds__(256) void bjorck_kernel(const float* __restrict__ W,
                                                     float* __restrict__ Wo) {
    __shared__ float w_s[DOUT * WROW];
    __shared__ float t_s[DOUT * WROW];
    __shared__ float g_s[DOUT * GROW];
    __shared__ float sc_s;
    int t = threadIdx.x;

    for (int idx = t; idx < DOUT * DIN; idx += 256) {
        int i = idx >> 7, k = idx & 127;
        w_s[i * WROW + k] = W[idx];
    }
    __syncthreads();

    compute_G(w_s, g_s, t);
    __syncthreads();

    // power iteration on G (64x64 SPD) within wave 0; G row held in registers
    if (t < 64) {
        float grow_r[64];
#pragma unroll
        for (int j = 0; j < 64; ++j) grow_r[j] = g_s[t * GROW + j];
        unsigned h = (unsigned)t * 2654435761u;
        float x = 0.5f + (float)((h >> 17) & 0x7fff) * (1.0f / 32768.0f);
        float lam = 1.0f;
        for (int it = 0; it < 96; ++it) {
            float y = 0.f;
#pragma unroll
            for (int j = 0; j < 64; ++j) y += grow_r[j] * __shfl(x, j);
            float n2 = y * y;
#pragma unroll
            for (int d = 1; d < 64; d <<= 1) n2 += __shfl_xor(n2, d);
            lam = sqrtf(n2);        // ||G x|| with ||x||=1  -> lambda_max
            x = y / lam;
        }
        if (t == 0) sc_s = 1.0f / (1.1f * sqrtf(lam));   // sigma = sqrt(lambda)
    }
    __syncthreads();
    float sc = sc_s;
    for (int idx = t; idx < DOUT * DIN; idx += 256) {
        int i = idx >> 7, k = idx & 127;
        w_s[i * WROW + k] *= sc;
    }

    for (int iter = 0; iter < 5; ++iter) {
        __syncthreads();
        compute_G(w_s, g_s, t);
        __syncthreads();
        // T = G @ w  (float4 over columns)
        for (int idx = t; idx < DOUT * (DIN / 4); idx += 256) {
            int i = idx >> 5, c4 = idx & 31;
            float4 acc = make_float4(0.f, 0.f, 0.f, 0.f);
#pragma unroll
            for (int j = 0; j < 64; ++j) {
                float g = g_s[i * GROW + j];
                float4 wv = *(const float4*)&w_s[j * WROW + c4 * 4];
                acc.x += g * wv.x; acc.y += g * wv.y;
                acc.z += g * wv.z; acc.w += g * wv.w;
            }
            *(float4*)&t_s[i * WROW + c4 * 4] = acc;
        }
        __syncthreads();
        for (int idx = t; idx < DOUT * DIN; idx += 256) {
            int i = idx >> 7, k = idx & 127;
            w_s[i * WROW + k] = 1.5f * w_s[i * WROW + k] - 0.5f * t_s[i * WROW + k];
        }
    }
    __syncthreads();
    for (int idx = t; idx < DOUT * DIN; idx += 256) {
        int i = idx >> 7, k = idx & 127;
        Wo[idx] = w_s[i * WROW + k];
    }
}

// ---------------------------------------------------------------------------
// Kernel 2: per-node prep
// ---------------------------------------------------------------------------
__global__ void node_prep(const float* __restrict__ diags,
                          const float* m1, const float* m2, const float* m3,
                          const float* e1, const float* e2, const float* e3,
                          float* __restrict__ d_e2m, float* __restrict__ d_e3p,
                          float* __restrict__ gso2, int n) {
    int i = blockIdx.x * blockDim.x + threadIdx.x;
    if (i >= n) return;
    float d = diags[i];
    float p1 = safe_pow(d, e1[0]);
    float p2 = safe_pow(d, e2[0]);
    float p3 = safe_pow(d, e3[0]);
    float vm2 = m2[0];
    d_e2m[i] = vm2 * p2;
    d_e3p[i] = p3;
    gso2[i] = m1[0] * p1 + vm2 * p2 * p3 + m3[0];
}

// ---------------------------------------------------------------------------
// Kernel 3: xw = x @ Wo^T
// ---------------------------------------------------------------------------
__global__ __launch_bounds__(256) void xw_kernel(const float* __restrict__ x,
                                                 const float* __restrict__ Wo,
                                                 float* __restrict__ xw, int n) {
    __shared__ float wo_s[DOUT * WROW];
    int t = threadIdx.x;
    for (int idx = t; idx < DOUT * DIN; idx += 256) {
        int i = idx >> 7, k = idx & 127;
        wo_s[i * WROW + k] = Wo[idx];
    }
    __syncthreads();
    int j = t & 63;
    int node = blockIdx.x * 4 + (t >> 6);
    if (node >= n) return;
    const float4* x4 = (const float4*)(x + (size_t)node * DIN);
    const float4* w4 = (const float4*)&wo_s[j * WROW];
    float acc = 0.f;
#pragma unroll
    for (int k = 0; k < DIN / 4; ++k) {
        float4 xv = x4[k], wv = w4[k];
        acc += xv.x * wv.x + xv.y * wv.y + xv.z * wv.z + xv.w * wv.w;
    }
    xw[(size_t)node * DOUT + j] = acc;
}

// ---------------------------------------------------------------------------
// Kernel 4: histogram of destination column
// ---------------------------------------------------------------------------
__global__ __launch_bounds__(256) void hist_kernel(const int* __restrict__ ei,
                                                   int* __restrict__ counts, int e_cnt) {
    int e = blockIdx.x * blockDim.x + threadIdx.x;
    if (e >= e_cnt) return;
    atomicAdd(&counts[ei[e_cnt + e]], 1);
}

// ---------------------------------------------------------------------------
// Kernel 5: single-block exclusive scan of counts -> offsets (n+1) and cursors
// ---------------------------------------------------------------------------
__global__ __launch_bounds__(1024) void scan_kernel(const int* __restrict__ counts,
                                                    int* __restrict__ offsets,
                                                    int* __restrict__ cursors, int n) {
    __shared__ int part[1024];
    int t = threadIdx.x;
    int chunk = (n + 1023) / 1024;
    int lo = t * chunk;
    int hi = min(lo + chunk, n);
    int s = 0;
    for (int i = lo; i < hi; ++i) s += counts[i];
    part[t] = s;
    __syncthreads();
    // inclusive Hillis-Steele scan in LDS
    for (int d = 1; d < 1024; d <<= 1) {
        int u = (t >= d) ? part[t - d] : 0;
        __syncthreads();
        part[t] += u;
        __syncthreads();
    }
    int run = part[t] - s;   // exclusive prefix of this thread's chunk
    for (int i = lo; i < hi; ++i) {
        offsets[i] = run;
        cursors[i] = run;
        run += counts[i];
    }
    if (t == 1023) offsets[n] = run;
}

// ---------------------------------------------------------------------------
// Kernel 6: reorder edges into CSR-by-col: (src row, edge weight)
// ---------------------------------------------------------------------------
__global__ __launch_bounds__(256) void reorder_kernel(const int* __restrict__ ei,
                                                      const float* __restrict__ d_e2m,
                                                      const float* __restrict__ d_e3p,
                                                      int* __restrict__ cursors,
                                                      int* __restrict__ srcs,
                                                      float* __restrict__ wts, int e_cnt) {
    int e = blockIdx.x * blockDim.x + threadIdx.x;
    if (e >= e_cnt) return;
    int row = ei[e];
    int col = ei[e_cnt + e];
    int pos = atomicAdd(&cursors[col], 1);
    srcs[pos] = row;
    wts[pos] = d_e2m[row] * d_e3p[col];
}

// ---------------------------------------------------------------------------
// Kernel 7: fused gather + self-loop + bias + log-softmax
// One 64-lane wave per node; lane = output dim.
// ---------------------------------------------------------------------------
__global__ __launch_bounds__(256) void gather_kernel(const int* __restrict__ offsets,
                                                     const int* __restrict__ srcs,
                                                     const float* __restrict__ wts,
                                                     const float* __restrict__ xw,
                                                     const float* __restrict__ gso2,
                                                     const float* __restrict__ b,
                                                     float* __restrict__ out, int n) {
    int lane = threadIdx.x & 63;
    int node = blockIdx.x * 4 + (threadIdx.x >> 6);
    if (node >= n) return;
    int lo = offsets[node], hi = offsets[node + 1];
    float v = gso2[node] * xw[(size_t)node * DOUT + lane] + 2.0f * b[lane];
    int i = lo;
    // 2-wide unroll: two independent gather chains in flight
    for (; i + 1 < hi; i += 2) {
        int s0 = srcs[i], s1 = srcs[i + 1];
        float w0 = wts[i], w1 = wts[i + 1];
        float a0 = xw[(size_t)s0 * DOUT + lane];
        float a1 = xw[(size_t)s1 * DOUT + lane];
        v += w0 * a0 + w1 * a1;
    }
    if (i < hi) v += wts[i] * xw[(size_t)srcs[i] * DOUT + lane];
    // log-softmax across the 64 lanes
    float m = v;
#pragma unroll
    for (int d = 1; d < 64; d <<= 1) m = fmaxf(m, __shfl_xor(m, d));
    float s = expf(v - m);
#pragma unroll
    for (int d = 1; d < 64; d <<= 1) s += __shfl_xor(s, d);
    out[(size_t)node * DOUT + lane] = v - m - logf(s);
}

// ---------------------------------------------------------------------------
extern "C" void kernel_launch(void* const* d_in, const int* in_sizes, int n_in,
                              void* d_out, int out_size, void* d_ws, size_t ws_size,
                              hipStream_t stream) {
    const float* x     = (const float*)d_in[0];
    const int*   ei    = (const int*)d_in[1];
    // d_in[2] = edge_index_id (arange self loops) -> handled analytically
    const float* diags = (const float*)d_in[3];
    const float* W     = (const float*)d_in[4];
    const float* b     = (const float*)d_in[5];
    const float* m1    = (const float*)d_in[6];
    const float* m2    = (const float*)d_in[7];
    const float* m3    = (const float*)d_in[8];
    const float* e1    = (const float*)d_in[9];
    const float* e2    = (const float*)d_in[10];
    const float* e3    = (const float*)d_in[11];
    float* out = (float*)d_out;

    const int n = in_sizes[3];          // 100000 nodes
    const int e_cnt = in_sizes[1] / 2;  // 1600000 edges

    char* ws = (char*)d_ws;
    float* Wo      = (float*)ws;                       // 8K floats (32KB)
    float* d_e2m   = (float*)(ws + 32768);             // n
    float* d_e3p   = d_e2m + n;                        // n
    float* gso2    = d_e3p + n;                        // n
    float* xw      = gso2 + n;                         // n*64
    int*   counts  = (int*)(xw + (size_t)n * DOUT);    // n
    int*   offsets = counts + n;                       // n+1
    int*   cursors = offsets + n + 1;                  // n
    int*   srcs    = cursors + n;                      // e_cnt
    float* wts     = (float*)(srcs + e_cnt);           // e_cnt

    // counts must start at zero every call
    hipMemsetAsync(counts, 0, (size_t)n * sizeof(int), stream);

    bjorck_kernel<<<1, 256, 0, stream>>>(W, Wo);
    node_prep<<<(n + 255) / 256, 256, 0, stream>>>(diags, m1, m2, m3, e1, e2, e3,
                                                   d_e2m, d_e3p, gso2, n);
    xw_kernel<<<(n + 3) / 4, 256, 0, stream>>>(x, Wo, xw, n);
    hist_kernel<<<(e_cnt + 255) / 256, 256, 0, stream>>>(ei, counts, e_cnt);
    scan_kernel<<<1, 1024, 0, stream>>>(counts, offsets, cursors, n);
    reorder_kernel<<<(e_cnt + 255) / 256, 256, 0, stream>>>(ei, d_e2m, d_e3p,
                                                            cursors, srcs, wts, e_cnt);
    gather_kernel<<<(n + 3) / 4, 256, 0, stream>>>(offsets, srcs, wts, xw, gso2, b,
                                                   out, n);
}

// Round 3
// 464.584 us; speedup vs baseline: 1.8834x; 1.8834x over previous
//
#include <hip/hip_runtime.h>
#include <math.h>

#define DIN 128
#define DOUT 64
#define GR 68               // 64x64 LDS row stride (floats), 16B-aligned rows

__device__ __forceinline__ float safe_pow(float d, float e) {
    float p = powf(d, e);
    return isinf(p) ? 0.0f : p;
}

__device__ __forceinline__ float dot4(float4 a, float4 b) {
    return a.x * b.x + a.y * b.y + a.z * b.z + a.w * b.w;
}

// C = A @ B for 64x64 LDS matrices, REQUIRES B symmetric (rows read as cols).
// 256 threads, each computes a 4x4 tile via float4 dots.
__device__ __forceinline__ void mm64(const float* A, const float* Bs, float* C, int t) {
    int ti = (t >> 4) * 4, tj = (t & 15) * 4;
    float acc[4][4] = {};
    for (int k4 = 0; k4 < 16; ++k4) {
        float4 a[4], bb[4];
#pragma unroll
        for (int r = 0; r < 4; ++r) a[r] = *(const float4*)&A[(ti + r) * GR + k4 * 4];
#pragma unroll
        for (int c = 0; c < 4; ++c) bb[c] = *(const float4*)&Bs[(tj + c) * GR + k4 * 4];
#pragma unroll
        for (int r = 0; r < 4; ++r)
#pragma unroll
            for (int c = 0; c < 4; ++c) acc[r][c] += dot4(a[r], bb[c]);
    }
#pragma unroll
    for (int r = 0; r < 4; ++r)
#pragma unroll
        for (int c = 0; c < 4; ++c) C[(ti + r) * GR + tj + c] = acc[r][c];
}

// ---------------------------------------------------------------------------
// Bjorck via Gram-domain iteration:
//   G = W W^T; lam = lambda_max(G); A0 = G/(1.21*lam)  (= w w^T for w=W/(1.1s))
//   iterate: B=1.5I-0.5A; P=P@B; A=A@B@B   (all symmetric, commute)
//   Wo = (1/(1.1s)) * P @ W
// ---------------------------------------------------------------------------
__global__ __launch_bounds__(256) void bjorck_kernel(const float* __restrict__ W,
                                                     float* __restrict__ Wo) {
    __shared__ __align__(16) float A0[DOUT * GR];
    __shared__ __align__(16) float A1[DOUT * GR];
    __shared__ __align__(16) float P0[DOUT * GR];
    __shared__ __align__(16) float P1[DOUT * GR];
    __shared__ __align__(16) float Bm[DOUT * GR];
    __shared__ float sc_sh, rs_sh;
    int t = threadIdx.x;

    // G = W W^T (W read straight from global; 32KB, L1/L2 resident)
    {
        int ti = (t >> 4) * 4, tj = (t & 15) * 4;
        float acc[4][4] = {};
        for (int k4 = 0; k4 < DIN / 4; ++k4) {
            float4 a[4], bb[4];
#pragma unroll
            for (int r = 0; r < 4; ++r) a[r] = *(const float4*)&W[(ti + r) * DIN + k4 * 4];
#pragma unroll
            for (int c = 0; c < 4; ++c) bb[c] = *(const float4*)&W[(tj + c) * DIN + k4 * 4];
#pragma unroll
            for (int r = 0; r < 4; ++r)
#pragma unroll
                for (int c = 0; c < 4; ++c) acc[r][c] += dot4(a[r], bb[c]);
        }
#pragma unroll
        for (int r = 0; r < 4; ++r)
#pragma unroll
            for (int c = 0; c < 4; ++c) A0[(ti + r) * GR + tj + c] = acc[r][c];
    }
    __syncthreads();

    // power iteration on G within wave 0 (G rows in registers)
    if (t < 64) {
        float4 g4[16];
#pragma unroll
        for (int j4 = 0; j4 < 16; ++j4) g4[j4] = *(const float4*)&A0[t * GR + j4 * 4];
        unsigned h = (unsigned)t * 2654435761u;
        float xv = 0.5f + (float)((h >> 17) & 0x7fff) * (1.0f / 32768.0f);
        float lam = 1.0f;
        for (int it = 0; it < 32; ++it) {
            float y = 0.f;
#pragma unroll
            for (int j4 = 0; j4 < 16; ++j4) {
                float4 xx;
                xx.x = __shfl(xv, j4 * 4 + 0);
                xx.y = __shfl(xv, j4 * 4 + 1);
                xx.z = __shfl(xv, j4 * 4 + 2);
                xx.w = __shfl(xv, j4 * 4 + 3);
                y += dot4(g4[j4], xx);
            }
            float n2 = y * y;
#pragma unroll
            for (int d = 1; d < 64; d <<= 1) n2 += __shfl_xor(n2, d);
            lam = sqrtf(n2);
            xv = y / lam;
        }
        if (t == 0) {
            rs_sh = 1.0f / (1.21f * lam);           // 1/(1.1^2 * sigma^2)
            sc_sh = 1.0f / (1.1f * sqrtf(lam));     // 1/(1.1 * sigma)
        }
    }
    __syncthreads();
    float rs = rs_sh;
    for (int q = t; q < DOUT * 64; q += 256) {
        int i = q >> 6, j = q & 63;
        A0[i * GR + j] *= rs;
    }
    __syncthreads();

    float *Acur = A0, *Aalt = A1, *Pcur = P0, *Palt = P1;
    for (int it = 0; it < 5; ++it) {
        // B = 1.5 I - 0.5 A
        for (int q = t; q < DOUT * 64; q += 256) {
            int i = q >> 6, j = q & 63;
            Bm[i * GR + j] = (i == j ? 1.5f : 0.0f) - 0.5f * Acur[i * GR + j];
        }
        __syncthreads();
        if (it == 0) {
            for (int q = t; q < DOUT * 64; q += 256) {
                int i = q >> 6, j = q & 63;
                Pcur[i * GR + j] = Bm[i * GR + j];
            }
        } else {
            mm64(Pcur, Bm, Palt, t);
        }
        __syncthreads();
        if (it != 0) { float* tmp = Pcur; Pcur = Palt; Palt = tmp; }
        // T = B@B into the dead P buffer
        mm64(Bm, Bm, Palt, t);
        __syncthreads();
        mm64(Acur, Palt, Aalt, t);
        __syncthreads();
        float* tmp = Acur; Acur = Aalt; Aalt = tmp;
    }

    // Wo = sc * P @ W   (64 x 128)
    float sc = sc_sh;
    {
        int i0 = (t >> 4) * 4;
        int k0 = (t & 15) * 8;
        float4 acc0[4] = {}, acc1[4] = {};
        for (int j = 0; j < 64; ++j) {
            float4 w0 = *(const float4*)&W[j * DIN + k0];
            float4 w1 = *(const float4*)&W[j * DIN + k0 + 4];
#pragma unroll
            for (int r = 0; r < 4; ++r) {
                float pv = Pcur[(i0 + r) * GR + j];
                acc0[r].x += pv * w0.x; acc0[r].y += pv * w0.y;
                acc0[r].z += pv * w0.z; acc0[r].w += pv * w0.w;
                acc1[r].x += pv * w1.x; acc1[r].y += pv * w1.y;
                acc1[r].z += pv * w1.z; acc1[r].w += pv * w1.w;
            }
        }
#pragma unroll
        for (int r = 0; r < 4; ++r) {
            float4 o0 = make_float4(sc * acc0[r].x, sc * acc0[r].y, sc * acc0[r].z, sc * acc0[r].w);
            float4 o1 = make_float4(sc * acc1[r].x, sc * acc1[r].y, sc * acc1[r].z, sc * acc1[r].w);
            *(float4*)&Wo[(i0 + r) * DIN + k0] = o0;
            *(float4*)&Wo[(i0 + r) * DIN + k0 + 4] = o1;
        }
    }
}

// ---------------------------------------------------------------------------
// per-node prep
// ---------------------------------------------------------------------------
__global__ void node_prep(const float* __restrict__ diags,
                          const float* m1, const float* m2, const float* m3,
                          const float* e1, const float* e2, const float* e3,
                          float* __restrict__ d_e2m, float* __restrict__ d_e3p,
                          float* __restrict__ gso2, int n) {
    int i = blockIdx.x * blockDim.x + threadIdx.x;
    if (i >= n) return;
    float d = diags[i];
    float p1 = safe_pow(d, e1[0]);
    float p2 = safe_pow(d, e2[0]);
    float p3 = safe_pow(d, e3[0]);
    float vm2 = m2[0];
    d_e2m[i] = vm2 * p2;
    d_e3p[i] = p3;
    gso2[i] = m1[0] * p1 + vm2 * p2 * p3 + m3[0];
}

// ---------------------------------------------------------------------------
// xw = x @ Wo^T : one wave per node
// ---------------------------------------------------------------------------
#define WROW 132
__global__ __launch_bounds__(256) void xw_kernel(const float* __restrict__ x,
                                                 const float* __restrict__ Wo,
                                                 float* __restrict__ xw, int n) {
    __shared__ __align__(16) float wo_s[DOUT * WROW];
    int t = threadIdx.x;
    for (int idx = t; idx < DOUT * DIN; idx += 256) {
        int i = idx >> 7, k = idx & 127;
        wo_s[i * WROW + k] = Wo[idx];
    }
    __syncthreads();
    int j = t & 63;
    int node = blockIdx.x * 4 + (t >> 6);
    if (node >= n) return;
    const float4* x4 = (const float4*)(x + (size_t)node * DIN);
    const float4* w4 = (const float4*)&wo_s[j * WROW];
    float acc = 0.f;
#pragma unroll
    for (int k = 0; k < DIN / 4; ++k) {
        float4 xv = x4[k], wv = w4[k];
        acc += xv.x * wv.x + xv.y * wv.y + xv.z * wv.z + xv.w * wv.w;
    }
    xw[(size_t)node * DOUT + j] = acc;
}

// ---------------------------------------------------------------------------
// histogram of destination column
// ---------------------------------------------------------------------------
__global__ __launch_bounds__(256) void hist_kernel(const int* __restrict__ ei,
                                                   int* __restrict__ counts, int e_cnt) {
    int e = blockIdx.x * blockDim.x + threadIdx.x;
    if (e >= e_cnt) return;
    atomicAdd(&counts[ei[e_cnt + e]], 1);
}

// ---------------------------------------------------------------------------
// 3-phase scan: block partial sums -> scan partials -> write offsets+cursors
// ---------------------------------------------------------------------------
__global__ __launch_bounds__(256) void scan_partial(const int* __restrict__ counts,
                                                    int* __restrict__ partials, int n) {
    __shared__ int wsum[4];
    int b = blockIdx.x, t = threadIdx.x;
    int base = b * 1024 + t * 4;
    int s = 0;
    if (base + 4 <= n) {
        int4 v = *(const int4*)&counts[base];
        s = v.x + v.y + v.z + v.w;
    } else {
        for (int i = base; i < n; ++i) s += counts[i];
    }
#pragma unroll
    for (int d = 1; d < 64; d <<= 1) s += __shfl_xor(s, d);
    if ((t & 63) == 0) wsum[t >> 6] = s;
    __syncthreads();
    if (t == 0) partials[b] = wsum[0] + wsum[1] + wsum[2] + wsum[3];
}

__global__ __launch_bounds__(128) void scan_mid(const int* __restrict__ partials,
                                                int* __restrict__ blk_off, int nb) {
    __shared__ int sh[128];
    int t = threadIdx.x;
    int v = (t < nb) ? partials[t] : 0;
    sh[t] = v;
    __syncthreads();
    for (int d = 1; d < 128; d <<= 1) {
        int u = (t >= d) ? sh[t - d] : 0;
        __syncthreads();
        sh[t] += u;
        __syncthreads();
    }
    if (t < nb) blk_off[t] = sh[t] - v;   // exclusive prefix of block sums
}

__global__ __launch_bounds__(256) void scan_write(const int* __restrict__ counts,
                                                  const int* __restrict__ blk_off,
                                                  int* __restrict__ offsets,
                                                  int* __restrict__ cursors,
                                                  int n, int e_cnt) {
    __shared__ int sh[256];
    int b = blockIdx.x, t = threadIdx.x;
    int base = b * 1024 + t * 4;
    int4 v = make_int4(0, 0, 0, 0);
    bool full = (base + 4 <= n);
    if (full) {
        v = *(const int4*)&counts[base];
    } else {
        int* vv = &v.x;
        for (int i = 0; i < 4; ++i) vv[i] = (base + i < n) ? counts[base + i] : 0;
    }
    int s = v.x + v.y + v.z + v.w;
    sh[t] = s;
    __syncthreads();
    for (int d = 1; d < 256; d <<= 1) {
        int u = (t >= d) ? sh[t - d] : 0;
        __syncthreads();
        sh[t] += u;
        __syncthreads();
    }
    int run = blk_off[b] + sh[t] - s;
    int4 o;
    o.x = run;
    o.y = run + v.x;
    o.z = o.y + v.y;
    o.w = o.z + v.z;
    if (full) {
        *(int4*)&offsets[base] = o;
        *(int4*)&cursors[base] = o;
    } else {
        int* oo = &o.x;
        for (int i = 0; i < 4; ++i)
            if (base + i < n) { offsets[base + i] = oo[i]; cursors[base + i] = oo[i]; }
    }
    if (b == 0 && t == 0) offsets[n] = e_cnt;
}

// ---------------------------------------------------------------------------
// reorder edges into CSR-by-col as interleaved (src, weight) int2 pairs
// ---------------------------------------------------------------------------
__global__ __launch_bounds__(256) void reorder_kernel(const int* __restrict__ ei,
                                                      const float* __restrict__ d_e2m,
                                                      const float* __restrict__ d_e3p,
                                                      int* __restrict__ cursors,
                                                      int2* __restrict__ pairs, int e_cnt) {
    int e = blockIdx.x * blockDim.x + threadIdx.x;
    if (e >= e_cnt) return;
    int row = ei[e];
    int col = ei[e_cnt + e];
    int pos = atomicAdd(&cursors[col], 1);
    int2 p;
    p.x = row;
    p.y = __float_as_int(d_e2m[row] * d_e3p[col]);
    pairs[pos] = p;
}

// ---------------------------------------------------------------------------
// fused gather + self-loop + bias + log-softmax; one wave per node
// ---------------------------------------------------------------------------
__global__ __launch_bounds__(256) void gather_kernel(const int* __restrict__ offsets,
                                                     const int2* __restrict__ pairs,
                                                     const float* __restrict__ xw,
                                                     const float* __restrict__ gso2,
                                                     const float* __restrict__ b,
                                                     float* __restrict__ out, int n) {
    int lane = threadIdx.x & 63;
    int node = blockIdx.x * 4 + (threadIdx.x >> 6);
    if (node >= n) return;
    int lo = offsets[node], hi = offsets[node + 1];
    float v = gso2[node] * xw[(size_t)node * DOUT + lane] + 2.0f * b[lane];
    int i = lo;
    for (; i + 4 <= hi; i += 4) {
        int2 p0 = pairs[i], p1 = pairs[i + 1], p2 = pairs[i + 2], p3 = pairs[i + 3];
        float a0 = xw[(size_t)p0.x * DOUT + lane];
        float a1 = xw[(size_t)p1.x * DOUT + lane];
        float a2 = xw[(size_t)p2.x * DOUT + lane];
        float a3 = xw[(size_t)p3.x * DOUT + lane];
        v += __int_as_float(p0.y) * a0 + __int_as_float(p1.y) * a1
           + __int_as_float(p2.y) * a2 + __int_as_float(p3.y) * a3;
    }
    for (; i < hi; ++i) {
        int2 p = pairs[i];
        v += __int_as_float(p.y) * xw[(size_t)p.x * DOUT + lane];
    }
    float m = v;
#pragma unroll
    for (int d = 1; d < 64; d <<= 1) m = fmaxf(m, __shfl_xor(m, d));
    float s = expf(v - m);
#pragma unroll
    for (int d = 1; d < 64; d <<= 1) s += __shfl_xor(s, d);
    out[(size_t)node * DOUT + lane] = v - m - logf(s);
}

// ---------------------------------------------------------------------------
extern "C" void kernel_launch(void* const* d_in, const int* in_sizes, int n_in,
                              void* d_out, int out_size, void* d_ws, size_t ws_size,
                              hipStream_t stream) {
    const float* x     = (const float*)d_in[0];
    const int*   ei    = (const int*)d_in[1];
    const float* diags = (const float*)d_in[3];
    const float* W     = (const float*)d_in[4];
    const float* b     = (const float*)d_in[5];
    const float* m1    = (const float*)d_in[6];
    const float* m2    = (const float*)d_in[7];
    const float* m3    = (const float*)d_in[8];
    const float* e1    = (const float*)d_in[9];
    const float* e2    = (const float*)d_in[10];
    const float* e3    = (const float*)d_in[11];
    float* out = (float*)d_out;

    const int n = in_sizes[3];          // 100000
    const int e_cnt = in_sizes[1] / 2;  // 1600000
    const int nb = (n + 1023) / 1024;   // scan blocks

    char* ws = (char*)d_ws;
    float* Wo       = (float*)ws;                       // 8K floats
    float* d_e2m    = (float*)(ws + 32768);             // n
    float* d_e3p    = d_e2m + n;                        // n
    float* gso2     = d_e3p + n;                        // n
    float* xw       = gso2 + n;                         // n*64
    int*   counts   = (int*)(xw + (size_t)n * DOUT);    // n (16B aligned)
    int*   offsets  = counts + n;                       // n+4
    int*   cursors  = offsets + n + 4;                  // n
    int*   partials = cursors + n;                      // 128
    int*   blk_off  = partials + 128;                   // 128
    uintptr_t pp = ((uintptr_t)(blk_off + 128) + 15) & ~(uintptr_t)15;
    int2*  pairs    = (int2*)pp;                        // e_cnt

    hipMemsetAsync(counts, 0, (size_t)n * sizeof(int), stream);

    bjorck_kernel<<<1, 256, 0, stream>>>(W, Wo);
    node_prep<<<(n + 255) / 256, 256, 0, stream>>>(diags, m1, m2, m3, e1, e2, e3,
                                                   d_e2m, d_e3p, gso2, n);
    xw_kernel<<<(n + 3) / 4, 256, 0, stream>>>(x, Wo, xw, n);
    hist_kernel<<<(e_cnt + 255) / 256, 256, 0, stream>>>(ei, counts, e_cnt);
    scan_partial<<<nb, 256, 0, stream>>>(counts, partials, n);
    scan_mid<<<1, 128, 0, stream>>>(partials, blk_off, nb);
    scan_write<<<nb, 256, 0, stream>>>(counts, blk_off, offsets, cursors, n, e_cnt);
    reorder_kernel<<<(e_cnt + 255) / 256, 256, 0, stream>>>(ei, d_e2m, d_e3p,
                                                            cursors, pairs, e_cnt);
    gather_kernel<<<(n + 3) / 4, 256, 0, stream>>>(offsets, pairs, xw, gso2, b,
                                                   out, n);
}

// Round 4
// 365.561 us; speedup vs baseline: 2.3936x; 1.2709x over previous
//
#include <hip/hip_runtime.h>
#include <math.h>

#define DIN 128
#define DOUT 64
#define GR 68               // 64x64 LDS row stride (floats), 16B-aligned rows

__device__ __forceinline__ float safe_pow(float d, float e) {
    float p = powf(d, e);
    return isinf(p) ? 0.0f : p;
}

__device__ __forceinline__ float dot4(float4 a, float4 b) {
    return a.x * b.x + a.y * b.y + a.z * b.z + a.w * b.w;
}

// C = A @ B for 64x64 LDS matrices, REQUIRES B symmetric (rows read as cols).
__device__ __forceinline__ void mm64(const float* A, const float* Bs, float* C, int t) {
    int ti = (t >> 4) * 4, tj = (t & 15) * 4;
    float acc[4][4] = {};
    for (int k4 = 0; k4 < 16; ++k4) {
        float4 a[4], bb[4];
#pragma unroll
        for (int r = 0; r < 4; ++r) a[r] = *(const float4*)&A[(ti + r) * GR + k4 * 4];
#pragma unroll
        for (int c = 0; c < 4; ++c) bb[c] = *(const float4*)&Bs[(tj + c) * GR + k4 * 4];
#pragma unroll
        for (int r = 0; r < 4; ++r)
#pragma unroll
            for (int c = 0; c < 4; ++c) acc[r][c] += dot4(a[r], bb[c]);
    }
#pragma unroll
    for (int r = 0; r < 4; ++r)
#pragma unroll
        for (int c = 0; c < 4; ++c) C[(ti + r) * GR + tj + c] = acc[r][c];
}

// ---------------------------------------------------------------------------
// Bjorck via Gram-domain iteration (single workgroup):
//   G = W W^T; lam = lambda_max(G); A0 = G/(1.21*lam)
//   iterate: B=1.5I-0.5A; P=P@B; A=A@B@B; Wo = sc * P @ W
// ---------------------------------------------------------------------------
__global__ __launch_bounds__(256) void bjorck_kernel(const float* __restrict__ W,
                                                     float* __restrict__ Wo) {
    __shared__ __align__(16) float A0[DOUT * GR];
    __shared__ __align__(16) float A1[DOUT * GR];
    __shared__ __align__(16) float P0[DOUT * GR];
    __shared__ __align__(16) float P1[DOUT * GR];
    __shared__ __align__(16) float Bm[DOUT * GR];
    __shared__ float sc_sh, rs_sh;
    int t = threadIdx.x;

    // G = W W^T
    {
        int ti = (t >> 4) * 4, tj = (t & 15) * 4;
        float acc[4][4] = {};
        for (int k4 = 0; k4 < DIN / 4; ++k4) {
            float4 a[4], bb[4];
#pragma unroll
            for (int r = 0; r < 4; ++r) a[r] = *(const float4*)&W[(ti + r) * DIN + k4 * 4];
#pragma unroll
            for (int c = 0; c < 4; ++c) bb[c] = *(const float4*)&W[(tj + c) * DIN + k4 * 4];
#pragma unroll
            for (int r = 0; r < 4; ++r)
#pragma unroll
                for (int c = 0; c < 4; ++c) acc[r][c] += dot4(a[r], bb[c]);
        }
#pragma unroll
        for (int r = 0; r < 4; ++r)
#pragma unroll
            for (int c = 0; c < 4; ++c) A0[(ti + r) * GR + tj + c] = acc[r][c];
    }
    __syncthreads();

    // power iteration on G within wave 0
    if (t < 64) {
        float4 g4[16];
#pragma unroll
        for (int j4 = 0; j4 < 16; ++j4) g4[j4] = *(const float4*)&A0[t * GR + j4 * 4];
        unsigned h = (unsigned)t * 2654435761u;
        float xv = 0.5f + (float)((h >> 17) & 0x7fff) * (1.0f / 32768.0f);
        float lam = 1.0f;
        for (int it = 0; it < 32; ++it) {
            float y = 0.f;
#pragma unroll
            for (int j4 = 0; j4 < 16; ++j4) {
                float4 xx;
                xx.x = __shfl(xv, j4 * 4 + 0);
                xx.y = __shfl(xv, j4 * 4 + 1);
                xx.z = __shfl(xv, j4 * 4 + 2);
                xx.w = __shfl(xv, j4 * 4 + 3);
                y += dot4(g4[j4], xx);
            }
            float n2 = y * y;
#pragma unroll
            for (int d = 1; d < 64; d <<= 1) n2 += __shfl_xor(n2, d);
            lam = sqrtf(n2);
            xv = y / lam;
        }
        if (t == 0) {
            rs_sh = 1.0f / (1.21f * lam);
            sc_sh = 1.0f / (1.1f * sqrtf(lam));
        }
    }
    __syncthreads();
    float rs = rs_sh;
    for (int q = t; q < DOUT * 64; q += 256) {
        int i = q >> 6, j = q & 63;
        A0[i * GR + j] *= rs;
    }
    __syncthreads();

    float *Acur = A0, *Aalt = A1, *Pcur = P0, *Palt = P1;
    for (int it = 0; it < 5; ++it) {
        for (int q = t; q < DOUT * 64; q += 256) {
            int i = q >> 6, j = q & 63;
            Bm[i * GR + j] = (i == j ? 1.5f : 0.0f) - 0.5f * Acur[i * GR + j];
        }
        __syncthreads();
        if (it == 0) {
            for (int q = t; q < DOUT * 64; q += 256) {
                int i = q >> 6, j = q & 63;
                Pcur[i * GR + j] = Bm[i * GR + j];
            }
        } else {
            mm64(Pcur, Bm, Palt, t);
        }
        __syncthreads();
        if (it != 0) { float* tmp = Pcur; Pcur = Palt; Palt = tmp; }
        mm64(Bm, Bm, Palt, t);        // T = B@B into dead buffer
        __syncthreads();
        mm64(Acur, Palt, Aalt, t);
        __syncthreads();
        float* tmp = Acur; Acur = Aalt; Aalt = tmp;
    }

    // Wo = sc * P @ W
    float sc = sc_sh;
    {
        int i0 = (t >> 4) * 4;
        int k0 = (t & 15) * 8;
        float4 acc0[4] = {}, acc1[4] = {};
        for (int j = 0; j < 64; ++j) {
            float4 w0 = *(const float4*)&W[j * DIN + k0];
            float4 w1 = *(const float4*)&W[j * DIN + k0 + 4];
#pragma unroll
            for (int r = 0; r < 4; ++r) {
                float pv = Pcur[(i0 + r) * GR + j];
                acc0[r].x += pv * w0.x; acc0[r].y += pv * w0.y;
                acc0[r].z += pv * w0.z; acc0[r].w += pv * w0.w;
                acc1[r].x += pv * w1.x; acc1[r].y += pv * w1.y;
                acc1[r].z += pv * w1.z; acc1[r].w += pv * w1.w;
            }
        }
#pragma unroll
        for (int r = 0; r < 4; ++r) {
            float4 o0 = make_float4(sc * acc0[r].x, sc * acc0[r].y, sc * acc0[r].z, sc * acc0[r].w);
            float4 o1 = make_float4(sc * acc1[r].x, sc * acc1[r].y, sc * acc1[r].z, sc * acc1[r].w);
            *(float4*)&Wo[(i0 + r) * DIN + k0] = o0;
            *(float4*)&Wo[(i0 + r) * DIN + k0 + 4] = o1;
        }
    }
}

// ---------------------------------------------------------------------------
// per-node prep
// ---------------------------------------------------------------------------
__global__ void node_prep(const float* __restrict__ diags,
                          const float* m1, const float* m2, const float* m3,
                          const float* e1, const float* e2, const float* e3,
                          float* __restrict__ d_e2m, float* __restrict__ d_e3p,
                          float* __restrict__ gso2, int n) {
    int i = blockIdx.x * blockDim.x + threadIdx.x;
    if (i >= n) return;
    float d = diags[i];
    float p1 = safe_pow(d, e1[0]);
    float p2 = safe_pow(d, e2[0]);
    float p3 = safe_pow(d, e3[0]);
    float vm2 = m2[0];
    d_e2m[i] = vm2 * p2;
    d_e3p[i] = p3;
    gso2[i] = m1[0] * p1 + vm2 * p2 * p3 + m3[0];
}

// ---------------------------------------------------------------------------
// xw = x @ Wo^T — register-tiled GEMM.
// Block = 256 threads = 64-node tile; LDS-staged x tile + W; 4x4 per thread.
// Thread (tn,td) -> nodes {4tn+r}, dims {td+16c}  (16-stride dims keep LDS
// reads at worst 2-way bank-aliased, which is free).
// ---------------------------------------------------------------------------
#define XN 64
#define XS 132
__global__ __launch_bounds__(256) void xw_kernel(const float* __restrict__ x,
                                                 const float* __restrict__ Wo,
                                                 float* __restrict__ xw, int n) {
    __shared__ __align__(16) float xs[XN * XS];
    __shared__ __align__(16) float ws[DOUT * XS];
    int t = threadIdx.x;
    int base = blockIdx.x * XN;
    for (int f = t; f < DOUT * (DIN / 4); f += 256) {
        int r = f >> 5, c = f & 31;
        *(float4*)&ws[r * XS + c * 4] = *(const float4*)&Wo[r * DIN + c * 4];
    }
    for (int f = t; f < XN * (DIN / 4); f += 256) {
        int r = f >> 5, c = f & 31;
        int node = base + r;
        float4 v = make_float4(0.f, 0.f, 0.f, 0.f);
        if (node < n) v = *(const float4*)&x[(size_t)node * DIN + c * 4];
        *(float4*)&xs[r * XS + c * 4] = v;
    }
    __syncthreads();
    int tn = t >> 4;
    int td = t & 15;
    float acc[4][4] = {};
#pragma unroll 2
    for (int k4 = 0; k4 < DIN / 4; ++k4) {
        float4 a[4], w[4];
#pragma unroll
        for (int r = 0; r < 4; ++r) a[r] = *(const float4*)&xs[(tn * 4 + r) * XS + k4 * 4];
#pragma unroll
        for (int c = 0; c < 4; ++c) w[c] = *(const float4*)&ws[(td + c * 16) * XS + k4 * 4];
#pragma unroll
        for (int r = 0; r < 4; ++r)
#pragma unroll
            for (int c = 0; c < 4; ++c) acc[r][c] += dot4(a[r], w[c]);
    }
#pragma unroll
    for (int r = 0; r < 4; ++r) {
        int node = base + tn * 4 + r;
        if (node >= n) break;
#pragma unroll
        for (int c = 0; c < 4; ++c)
            xw[(size_t)node * DOUT + td + c * 16] = acc[r][c];
    }
}

// ---------------------------------------------------------------------------
// histogram of destination column
// ---------------------------------------------------------------------------
__global__ __launch_bounds__(256) void hist_kernel(const int* __restrict__ ei,
                                                   int* __restrict__ counts, int e_cnt) {
    int e = blockIdx.x * blockDim.x + threadIdx.x;
    if (e >= e_cnt) return;
    atomicAdd(&counts[ei[e_cnt + e]], 1);
}

// ---------------------------------------------------------------------------
// 3-phase scan
// ---------------------------------------------------------------------------
__global__ __launch_bounds__(256) void scan_partial(const int* __restrict__ counts,
                                                    int* __restrict__ partials, int n) {
    __shared__ int wsum[4];
    int b = blockIdx.x, t = threadIdx.x;
    int base = b * 1024 + t * 4;
    int s = 0;
    if (base + 4 <= n) {
        int4 v = *(const int4*)&counts[base];
        s = v.x + v.y + v.z + v.w;
    } else {
        for (int i = base; i < n; ++i) s += counts[i];
    }
#pragma unroll
    for (int d = 1; d < 64; d <<= 1) s += __shfl_xor(s, d);
    if ((t & 63) == 0) wsum[t >> 6] = s;
    __syncthreads();
    if (t == 0) partials[b] = wsum[0] + wsum[1] + wsum[2] + wsum[3];
}

__global__ __launch_bounds__(128) void scan_mid(const int* __restrict__ partials,
                                                int* __restrict__ blk_off, int nb) {
    __shared__ int sh[128];
    int t = threadIdx.x;
    int v = (t < nb) ? partials[t] : 0;
    sh[t] = v;
    __syncthreads();
    for (int d = 1; d < 128; d <<= 1) {
        int u = (t >= d) ? sh[t - d] : 0;
        __syncthreads();
        sh[t] += u;
        __syncthreads();
    }
    if (t < nb) blk_off[t] = sh[t] - v;
}

__global__ __launch_bounds__(256) void scan_write(const int* __restrict__ counts,
                                                  const int* __restrict__ blk_off,
                                                  int* __restrict__ offsets,
                                                  int* __restrict__ cursors,
                                                  int n, int e_cnt) {
    __shared__ int sh[256];
    int b = blockIdx.x, t = threadIdx.x;
    int base = b * 1024 + t * 4;
    int4 v = make_int4(0, 0, 0, 0);
    bool full = (base + 4 <= n);
    if (full) {
        v = *(const int4*)&counts[base];
    } else {
        int* vv = &v.x;
        for (int i = 0; i < 4; ++i) vv[i] = (base + i < n) ? counts[base + i] : 0;
    }
    int s = v.x + v.y + v.z + v.w;
    sh[t] = s;
    __syncthreads();
    for (int d = 1; d < 256; d <<= 1) {
        int u = (t >= d) ? sh[t - d] : 0;
        __syncthreads();
        sh[t] += u;
        __syncthreads();
    }
    int run = blk_off[b] + sh[t] - s;
    int4 o;
    o.x = run;
    o.y = run + v.x;
    o.z = o.y + v.y;
    o.w = o.z + v.z;
    if (full) {
        *(int4*)&offsets[base] = o;
        *(int4*)&cursors[base] = o;
    } else {
        int* oo = &o.x;
        for (int i = 0; i < 4; ++i)
            if (base + i < n) { offsets[base + i] = oo[i]; cursors[base + i] = oo[i]; }
    }
    if (b == 0 && t == 0) offsets[n] = e_cnt;
}

// ---------------------------------------------------------------------------
// reorder edges into CSR-by-col as interleaved (src, weight) int2 pairs
// ---------------------------------------------------------------------------
__global__ __launch_bounds__(256) void reorder_kernel(const int* __restrict__ ei,
                                                      const float* __restrict__ d_e2m,
                                                      const float* __restrict__ d_e3p,
                                                      int* __restrict__ cursors,
                                                      int2* __restrict__ pairs, int e_cnt) {
    int e = blockIdx.x * blockDim.x + threadIdx.x;
    if (e >= e_cnt) return;
    int row = ei[e];
    int col = ei[e_cnt + e];
    int pos = atomicAdd(&cursors[col], 1);
    int2 p;
    p.x = row;
    p.y = __float_as_int(d_e2m[row] * d_e3p[col]);
    pairs[pos] = p;
}

// ---------------------------------------------------------------------------
// fused gather + self-loop + bias + log-softmax; one wave per node
// ---------------------------------------------------------------------------
__global__ __launch_bounds__(256) void gather_kernel(const int* __restrict__ offsets,
                                                     const int2* __restrict__ pairs,
                                                     const float* __restrict__ xw,
                                                     const float* __restrict__ gso2,
                                                     const float* __restrict__ b,
                                                     float* __restrict__ out, int n) {
    int lane = threadIdx.x & 63;
    int node = blockIdx.x * 4 + (threadIdx.x >> 6);
    if (node >= n) return;
    int lo = offsets[node], hi = offsets[node + 1];
    float v = gso2[node] * xw[(size_t)node * DOUT + lane] + 2.0f * b[lane];
    int i = lo;
    for (; i + 4 <= hi; i += 4) {
        int2 p0 = pairs[i], p1 = pairs[i + 1], p2 = pairs[i + 2], p3 = pairs[i + 3];
        float a0 = xw[(size_t)p0.x * DOUT + lane];
        float a1 = xw[(size_t)p1.x * DOUT + lane];
        float a2 = xw[(size_t)p2.x * DOUT + lane];
        float a3 = xw[(size_t)p3.x * DOUT + lane];
        v += __int_as_float(p0.y) * a0 + __int_as_float(p1.y) * a1
           + __int_as_float(p2.y) * a2 + __int_as_float(p3.y) * a3;
    }
    for (; i < hi; ++i) {
        int2 p = pairs[i];
        v += __int_as_float(p.y) * xw[(size_t)p.x * DOUT + lane];
    }
    float m = v;
#pragma unroll
    for (int d = 1; d < 64; d <<= 1) m = fmaxf(m, __shfl_xor(m, d));
    float s = expf(v - m);
#pragma unroll
    for (int d = 1; d < 64; d <<= 1) s += __shfl_xor(s, d);
    out[(size_t)node * DOUT + lane] = v - m - logf(s);
}

// ---------------------------------------------------------------------------
extern "C" void kernel_launch(void* const* d_in, const int* in_sizes, int n_in,
                              void* d_out, int out_size, void* d_ws, size_t ws_size,
                              hipStream_t stream) {
    const float* x     = (const float*)d_in[0];
    const int*   ei    = (const int*)d_in[1];
    const float* diags = (const float*)d_in[3];
    const float* W     = (const float*)d_in[4];
    const float* b     = (const float*)d_in[5];
    const float* m1    = (const float*)d_in[6];
    const float* m2    = (const float*)d_in[7];
    const float* m3    = (const float*)d_in[8];
    const float* e1    = (const float*)d_in[9];
    const float* e2    = (const float*)d_in[10];
    const float* e3    = (const float*)d_in[11];
    float* out = (float*)d_out;

    const int n = in_sizes[3];          // 100000
    const int e_cnt = in_sizes[1] / 2;  // 1600000
    const int nb = (n + 1023) / 1024;   // scan blocks

    char* ws = (char*)d_ws;
    float* Wo       = (float*)ws;                       // 8K floats
    float* d_e2m    = (float*)(ws + 32768);             // n
    float* d_e3p    = d_e2m + n;                        // n
    float* gso2     = d_e3p + n;                        // n
    float* xw       = gso2 + n;                         // n*64
    int*   counts   = (int*)(xw + (size_t)n * DOUT);    // n
    int*   offsets  = counts + n;                       // n+4
    int*   cursors  = offsets + n + 4;                  // n
    int*   partials = cursors + n;                      // 128
    int*   blk_off  = partials + 128;                   // 128
    uintptr_t pp = ((uintptr_t)(blk_off + 128) + 15) & ~(uintptr_t)15;
    int2*  pairs    = (int2*)pp;                        // e_cnt

    hipMemsetAsync(counts, 0, (size_t)n * sizeof(int), stream);

    bjorck_kernel<<<1, 256, 0, stream>>>(W, Wo);
    node_prep<<<(n + 255) / 256, 256, 0, stream>>>(diags, m1, m2, m3, e1, e2, e3,
                                                   d_e2m, d_e3p, gso2, n);
    xw_kernel<<<(n + XN - 1) / XN, 256, 0, stream>>>(x, Wo, xw, n);
    hist_kernel<<<(e_cnt + 255) / 256, 256, 0, stream>>>(ei, counts, e_cnt);
    scan_partial<<<nb, 256, 0, stream>>>(counts, partials, n);
    scan_mid<<<1, 128, 0, stream>>>(partials, blk_off, nb);
    scan_write<<<nb, 256, 0, stream>>>(counts, blk_off, offsets, cursors, n, e_cnt);
    reorder_kernel<<<(e_cnt + 255) / 256, 256, 0, stream>>>(ei, d_e2m, d_e3p,
                                                            cursors, pairs, e_cnt);
    gather_kernel<<<(n + 3) / 4, 256, 0, stream>>>(offsets, pairs, xw, gso2, b,
                                                   out, n);
}